// Round 1
// 687.564 us; speedup vs baseline: 1.4029x; 1.4029x over previous
//
#include <hip/hip_runtime.h>
#include <math.h>

// GlmDSAMoEGate, round 4: move the router GEMM onto the matrix cores.
// fp32 has no MFMA on CDNA4 -> split each fp32 input into fp16 hi + fp16 lo*2^12
// (lo scaled so it never denormal-flushes). 3 MFMA passes:
//   accA += xh*wh ; accB += xh*wl + xl*wh ; logit = accA + accB * 2^-12
// Input-rounding error ~2^-24 relative -> logit error ~1e-7, below the fp32
// accumulation-reorder noise of the previous (passing) VALU kernel.
//
// Structure per block: 64 tokens x 256 experts, 4 waves, wave tile 64x64
// (2x2 of mfma_f32_32x32x16_f16), K-tile 64 (4 MFMA phases / tile).
//  - W pre-swizzled (kernel 0) into MFMA-fragment-linear hi/lo order in the
//    4MB workspace: B frags load L2->VGPR as fully-coalesced dwordx4 (1KB/instr),
//    B never touches LDS. Per-s-phase register double-buffer (b0/b1).
//  - A staged in LDS in fragment-linear hi/lo layout, double-buffered:
//    coalesced 64B/thread global read -> in-reg split -> 4x ds_write_b128
//    (chunk indices cover all 32 banks uniformly); frag reads are contiguous
//    1KB ds_read_b128. One __syncthreads per K-tile.
//  - Epilogue (sigmoid + grouped top-k) identical to the proven round-3 code,
//    widened to 64 tokens/block.

constexpr int H = 4096;
constexpr int E = 256;
constexpr int BM = 64;          // tokens per block
constexpr int NTH = 256;        // 4 waves
constexpr int TOPK = 8;
constexpr int NGROUP = 8;
constexpr int GSIZE = 32;
constexpr int TOPK_GROUP = 4;
constexpr float SCALE = 2.5f;
constexpr int NK16 = H / 16;    // 256 K16 slabs
constexpr int NT = H / 64;      // 64 K-tiles
constexpr float LO_SCALE = 4096.0f;       // 2^12
constexpr float LO_INV = 1.0f / 4096.0f;  // 2^-12

typedef _Float16 f16x8 __attribute__((ext_vector_type(8)));
typedef float f32x16 __attribute__((ext_vector_type(16)));

// ---------------- kernel 0: W[E][H] fp32 -> fragment-linear fp16 hi/lo ------
// Frag for MFMA 32x32x16 tile (k16, n32): lane l holds B[k][n] with
// n = n32*32 + (l&31), k = k16*16 + (l>>5)*8 + j, j=0..7  (16B per lane).
// Layout: wswz[(k16*8 + n32)*1024 + hl*512 + l*8]  (halves). Total 4MB.
__global__ __launch_bounds__(64)
void prep_w_kernel(const float* __restrict__ w, _Float16* __restrict__ wswz) {
  const int l = threadIdx.x;        // 0..63
  const int k16 = blockIdx.x;       // 0..255
  const int n32 = blockIdx.y;       // 0..7
  const int e = n32 * 32 + (l & 31);
  const int h0 = k16 * 16 + (l >> 5) * 8;
  const float4* wp = (const float4*)(w + (size_t)e * H + h0);
  const float4 a = wp[0], b = wp[1];
  const float v[8] = {a.x, a.y, a.z, a.w, b.x, b.y, b.z, b.w};
  f16x8 hi, lo;
#pragma unroll
  for (int j = 0; j < 8; ++j) {
    const _Float16 h = (_Float16)v[j];
    hi[j] = h;
    lo[j] = (_Float16)((v[j] - (float)h) * LO_SCALE);  // exact residual, scaled
  }
  _Float16* dst = wswz + (size_t)(k16 * 8 + n32) * 1024 + (size_t)l * 8;
  *(f16x8*)dst = hi;
  *(f16x8*)(dst + 512) = lo;
}

// ---------------- kernel 1: fused gate -------------------------------------
__global__ __launch_bounds__(NTH, 1)
void moe_gate_kernel(const float* __restrict__ x,      // [T][H] fp32
                     const _Float16* __restrict__ wswz,// frag-linear hi/lo
                     const float* __restrict__ bias,   // [E]
                     float* __restrict__ out_idx,      // [T][8] (as float)
                     float* __restrict__ out_w) {      // [T][8]
  // A staging: [buf][s(=k16 in tile)][mt][hl][lane-chunk*8]  = 32 KB
  __shared__ __align__(16) _Float16 a_st[2][4][2][2][512];
  __shared__ float val[BM][E + 1];   // scores_for_choice, 65792 B
  __shared__ float sbias[E];

  const int tid = threadIdx.x;
  const int lane = tid & 63;
  const int wave = tid >> 6;         // 0..3 -> expert slice [64*wave, +64)
  const long t0 = (long)blockIdx.x * BM;

  sbias[tid] = bias[tid];            // NTH == E

  // A staging coords: thread -> (token ta, k-16-slab kq), 16 floats = 64B.
  const int ta = tid >> 2;           // 0..63
  const int kq = tid & 3;            // 0..3  (== s phase index)
  const int c0 = ta & 31;            // lane-chunk (khalf 0); khalf 1 = c0+32
  const float4* xq = (const float4*)(x + (size_t)(t0 + ta) * H) + 4 * kq;
  _Float16* const aw0 = &a_st[0][kq][ta >> 5][0][0];
  _Float16* const aw1 = &a_st[1][kq][ta >> 5][0][0];
  // B frag base for this wave/lane: offsets (halves): k16g*8192 + nt*1024 + hl*512
  const _Float16* const bb = wswz + (size_t)wave * 2048 + (size_t)lane * 8;

  f32x16 accA[2][2], accB[2][2];
#pragma unroll
  for (int mt = 0; mt < 2; ++mt)
#pragma unroll
    for (int nt = 0; nt < 2; ++nt)
#pragma unroll
      for (int r = 0; r < 16; ++r) { accA[mt][nt][r] = 0.0f; accB[mt][nt][r] = 0.0f; }

  f16x8 b0[2][2], b1[2][2];   // [nt][hl], per-phase register double buffer

  auto writeA = [&](_Float16* base, const float4 q0, const float4 q1,
                    const float4 q2, const float4 q3) {
    const float v[16] = {q0.x, q0.y, q0.z, q0.w, q1.x, q1.y, q1.z, q1.w,
                         q2.x, q2.y, q2.z, q2.w, q3.x, q3.y, q3.z, q3.w};
    f16x8 h0v, l0v, h1v, l1v;
#pragma unroll
    for (int j = 0; j < 8; ++j) {
      const _Float16 h = (_Float16)v[j];
      h0v[j] = h;
      l0v[j] = (_Float16)((v[j] - (float)h) * LO_SCALE);
      const _Float16 h2 = (_Float16)v[8 + j];
      h1v[j] = h2;
      l1v[j] = (_Float16)((v[8 + j] - (float)h2) * LO_SCALE);
    }
    *(f16x8*)(base + (size_t)c0 * 8) = h0v;               // khalf 0, hi
    *(f16x8*)(base + (size_t)(c0 + 32) * 8) = h1v;        // khalf 1, hi
    *(f16x8*)(base + 512 + (size_t)c0 * 8) = l0v;         // khalf 0, lo
    *(f16x8*)(base + 512 + (size_t)(c0 + 32) * 8) = l1v;  // khalf 1, lo
  };

  auto phase = [&](int k16n, int s, int buf, f16x8 (&bc)[2][2], f16x8 (&bn)[2][2]) {
    if (k16n < NK16) {               // prefetch next phase's B frags (L2)
#pragma unroll
      for (int nt = 0; nt < 2; ++nt)
#pragma unroll
        for (int hl = 0; hl < 2; ++hl)
          bn[nt][hl] = *(const f16x8*)(bb + (size_t)k16n * 8192 + nt * 1024 + hl * 512);
    }
    f16x8 af[2][2];                  // [mt][hl]
#pragma unroll
    for (int mt = 0; mt < 2; ++mt)
#pragma unroll
      for (int hl = 0; hl < 2; ++hl)
        af[mt][hl] = *(const f16x8*)&a_st[buf][s][mt][hl][lane * 8];
#pragma unroll
    for (int mt = 0; mt < 2; ++mt)
#pragma unroll
      for (int nt = 0; nt < 2; ++nt) {
        accA[mt][nt] = __builtin_amdgcn_mfma_f32_32x32x16_f16(af[mt][0], bc[nt][0], accA[mt][nt], 0, 0, 0);
        accB[mt][nt] = __builtin_amdgcn_mfma_f32_32x32x16_f16(af[mt][0], bc[nt][1], accB[mt][nt], 0, 0, 0);
        accB[mt][nt] = __builtin_amdgcn_mfma_f32_32x32x16_f16(af[mt][1], bc[nt][0], accB[mt][nt], 0, 0, 0);
      }
  };

  // ---- prologue: tile 0 staged, first B phase loaded ----
  float4 q0 = xq[0], q1 = xq[1], q2 = xq[2], q3 = xq[3];
  xq += 16;
  writeA(aw0, q0, q1, q2, q3);
#pragma unroll
  for (int nt = 0; nt < 2; ++nt)
#pragma unroll
    for (int hl = 0; hl < 2; ++hl)
      b0[nt][hl] = *(const f16x8*)(bb + nt * 1024 + hl * 512);

  // ---- main loop: 64 K-tiles, 1 barrier each ----
#pragma unroll 1
  for (int t = 0; t < NT; ++t) {
    const int buf = t & 1;
    __syncthreads();                 // A[buf] visible; prev-tile reads retired
    if (t + 1 < NT) { q0 = xq[0]; q1 = xq[1]; q2 = xq[2]; q3 = xq[3]; xq += 16; }
    const int kb = 4 * t;
    phase(kb + 1, 0, buf, b0, b1);
    phase(kb + 2, 1, buf, b1, b0);
    phase(kb + 3, 2, buf, b0, b1);
    phase(kb + 4, 3, buf, b1, b0);   // loads (t+1, s=0) into b0
    if (t + 1 < NT) writeA(buf ? aw0 : aw1, q0, q1, q2, q3);
  }

  // ---- scores_for_choice into LDS ----
  // C layout (32x32 MFMA): col = lane&31, row = (r&3) + 8*(r>>2) + 4*(lane>>5)
  const int col = lane & 31;
  const int rbase = (lane >> 5) * 4;
#pragma unroll
  for (int mt = 0; mt < 2; ++mt)
#pragma unroll
    for (int nt = 0; nt < 2; ++nt) {
      const int e = wave * 64 + nt * 32 + col;
      const float be = sbias[e];
#pragma unroll
      for (int r = 0; r < 16; ++r) {
        const int row = (r & 3) + 8 * (r >> 2) + rbase;
        const float logit = accA[mt][nt][r] + accB[mt][nt][r] * LO_INV;
        const float s = 1.0f / (1.0f + expf(-logit));    // sigmoid
        val[mt * 32 + row][e] = s + be;                  // s_choice
      }
    }
  __syncthreads();

  // ---- per-token grouped top-k (1 thread/token, lax.top_k semantics) ----
  if (tid < BM) {
    const int t = tid;
    float gs[NGROUP];
#pragma unroll
    for (int g = 0; g < NGROUP; ++g) {
      float m1 = -1e30f, m2 = -1e30f;
      for (int jj = 0; jj < GSIZE; ++jj) {
        const float v = val[t][g * GSIZE + jj];
        if (v > m1) { m2 = m1; m1 = v; }
        else if (v > m2) { m2 = v; }
      }
      gs[g] = m1 + m2;
    }
    unsigned selmask = 0;
#pragma unroll
    for (int r = 0; r < TOPK_GROUP; ++r) {
      float best = -1e30f; int bg = 0;
#pragma unroll
      for (int g = 0; g < NGROUP; ++g) {
        if (((selmask >> g) & 1u) == 0 && gs[g] > best) { best = gs[g]; bg = g; }
      }
      selmask |= 1u << bg;
    }
    unsigned long long picked[4] = {0ull, 0ull, 0ull, 0ull};
    int idx[TOPK];
    float wts[TOPK];
    float wsum = 0.f;
    for (int r = 0; r < TOPK; ++r) {
      float best = -1e30f; int be = 0; bool found = false;
      for (int e = 0; e < E; ++e) {
        if ((picked[e >> 6] >> (e & 63)) & 1ull) continue;
        const float v = ((selmask >> (e >> 5)) & 1u) ? val[t][e] : 0.0f;
        if (!found || v > best) { best = v; be = e; found = true; }
      }
      picked[be >> 6] |= 1ull << (be & 63);
      idx[r] = be;
      const float s = val[t][be] - sbias[be];
      wts[r] = s;
      wsum += s;
    }
    const float inv = SCALE / (wsum + 1e-20f);
#pragma unroll
    for (int r = 0; r < TOPK; ++r) {
      out_idx[(t0 + t) * TOPK + r] = (float)idx[r];
      out_w[(t0 + t) * TOPK + r] = wts[r] * inv;
    }
  }
}

extern "C" void kernel_launch(void* const* d_in, const int* in_sizes, int n_in,
                              void* d_out, int out_size, void* d_ws, size_t ws_size,
                              hipStream_t stream) {
  const float* x = (const float*)d_in[0];     // (4,4096,4096) fp32
  const float* w = (const float*)d_in[1];     // (256,4096) fp32
  const float* bias = (const float*)d_in[2];  // (256,) fp32

  const int T = in_sizes[0] / H;              // 16384
  _Float16* wswz = (_Float16*)d_ws;           // 4 MB frag-linear hi/lo W
  float* out_idx = (float*)d_out;
  float* out_w = (float*)d_out + (size_t)T * TOPK;

  prep_w_kernel<<<dim3(NK16, E / 32), dim3(64), 0, stream>>>(w, wswz);
  moe_gate_kernel<<<dim3(T / BM), dim3(NTH), 0, stream>>>(x, wswz, bias, out_idx, out_w);
}

// Round 2
// 588.977 us; speedup vs baseline: 1.6377x; 1.1674x over previous
//
#include <hip/hip_runtime.h>
#include <math.h>

// GlmDSAMoEGate, round 5: fix the latency-bound launch shape of round 4.
// Round 4 (432us): 256 thr, 1 blk/CU, 1 wave/SIMD -> MfmaUtil 9.6%, Occ 8.2%,
// everything stalled on L2-latency B loads prefetched only 1 phase ahead.
// Round 5:
//  - 512 threads = 8 waves/block (2 waves/SIMD). Wave w owns expert slice
//    [32w, 32w+32) x all 64 tokens: acc = 2x(16 f32) per plane, 64 VGPR.
//  - B fragments double-buffered BY K-TILE (4 phases deep): loads issue a
//    full tile (~400+ cy) before consumption >> L2 latency. Tile loop
//    unrolled x2 so all register-array indices are compile-time (no scratch).
//  - x loads are non-temporal: protects the 4MB swizzled-W image in L2
//    (it exactly fits one XCD's L2) from the 256MB x stream.
// Math identical to round 4 (passed, absmax 2e-3): fp32 -> fp16 hi + lo*2^12
// split, 3 MFMA passes, logit = accA + accB*2^-12.

constexpr int H = 4096;
constexpr int E = 256;
constexpr int BM = 64;          // tokens per block
constexpr int NTH = 512;        // 8 waves
constexpr int TOPK = 8;
constexpr int NGROUP = 8;
constexpr int GSIZE = 32;
constexpr int TOPK_GROUP = 4;
constexpr float SCALE = 2.5f;
constexpr int NK16 = H / 16;    // 256 K16 slabs
constexpr int NT = H / 64;      // 64 K-tiles (must be even)
constexpr float LO_SCALE = 4096.0f;       // 2^12
constexpr float LO_INV = 1.0f / 4096.0f;  // 2^-12

typedef _Float16 f16x8 __attribute__((ext_vector_type(8)));
typedef float f32x4 __attribute__((ext_vector_type(4)));
typedef float f32x16 __attribute__((ext_vector_type(16)));

// ---------------- kernel 0: W[E][H] fp32 -> fragment-linear fp16 hi/lo ------
// Frag for MFMA 32x32x16 tile (k16, n32): lane l holds B[k][n] with
// n = n32*32 + (l&31), k = k16*16 + (l>>5)*8 + j, j=0..7  (16B per lane).
// Layout: wswz[(k16*8 + n32)*1024 + hl*512 + l*8]  (halves). Total 4MB.
__global__ __launch_bounds__(64)
void prep_w_kernel(const float* __restrict__ w, _Float16* __restrict__ wswz) {
  const int l = threadIdx.x;        // 0..63
  const int k16 = blockIdx.x;       // 0..255
  const int n32 = blockIdx.y;       // 0..7
  const int e = n32 * 32 + (l & 31);
  const int h0 = k16 * 16 + (l >> 5) * 8;
  const float4* wp = (const float4*)(w + (size_t)e * H + h0);
  const float4 a = wp[0], b = wp[1];
  const float v[8] = {a.x, a.y, a.z, a.w, b.x, b.y, b.z, b.w};
  f16x8 hi, lo;
#pragma unroll
  for (int j = 0; j < 8; ++j) {
    const _Float16 h = (_Float16)v[j];
    hi[j] = h;
    lo[j] = (_Float16)((v[j] - (float)h) * LO_SCALE);  // exact residual, scaled
  }
  _Float16* dst = wswz + (size_t)(k16 * 8 + n32) * 1024 + (size_t)l * 8;
  *(f16x8*)dst = hi;
  *(f16x8*)(dst + 512) = lo;
}

// ---------------- kernel 1: fused gate -------------------------------------
__global__ __launch_bounds__(NTH, 2)
void moe_gate_kernel(const float* __restrict__ x,      // [T][H] fp32
                     const _Float16* __restrict__ wswz,// frag-linear hi/lo
                     const float* __restrict__ bias,   // [E]
                     float* __restrict__ out_idx,      // [T][8] (as float)
                     float* __restrict__ out_w) {      // [T][8]
  // A staging: [buf][s(=k16 in tile)][mt][hl][512 halves] = 32 KB
  __shared__ __align__(16) _Float16 a_st[2][4][2][2][512];
  __shared__ float val[BM][E + 1];   // scores_for_choice, 65792 B
  __shared__ float sbias[E];

  const int tid = threadIdx.x;
  const int lane = tid & 63;
  const int wave = tid >> 6;         // 0..7 -> expert slice [32*wave, +32)
  const long t0 = (long)blockIdx.x * BM;

  if (tid < E) sbias[tid] = bias[tid];

  // A staging coords: thread -> (token ta, k-octet kq), 8 floats = 32B.
  const int ta = tid >> 3;           // 0..63 token
  const int kq = tid & 7;            // 0..7 k-octet within 64-k tile
  const int sA = kq >> 1;            // k16 phase 0..3
  const int khA = kq & 1;            // k-half within k16
  const int mtA = ta >> 5;           // token half
  const int cA = ta & 31;            // lane chunk
  _Float16* const awp = &a_st[0][sA][mtA][0][(khA * 32 + cA) * 8];
  const f32x4* xq = (const f32x4*)(x + (size_t)(t0 + ta) * H) + 2 * kq;

  // B frag base for this wave/lane; per k16 stride = 8192 halves
  const _Float16* const bb = wswz + (size_t)wave * 1024 + (size_t)lane * 8;

  f32x16 accA[2], accB[2];
#pragma unroll
  for (int mt = 0; mt < 2; ++mt)
#pragma unroll
    for (int r = 0; r < 16; ++r) { accA[mt][r] = 0.0f; accB[mt][r] = 0.0f; }

  f16x8 bE[4][2], bO[4][2];          // per-tile B register double buffer

  auto writeA = [&](int buf, f32x4 q0, f32x4 q1) {
    const float v[8] = {q0[0], q0[1], q0[2], q0[3], q1[0], q1[1], q1[2], q1[3]};
    f16x8 hv, lv;
#pragma unroll
    for (int j = 0; j < 8; ++j) {
      const _Float16 h = (_Float16)v[j];
      hv[j] = h;
      lv[j] = (_Float16)((v[j] - (float)h) * LO_SCALE);
    }
    _Float16* p = awp + (size_t)buf * 8192;  // a_st[buf] stride in halves
    *(f16x8*)p = hv;
    *(f16x8*)(p + 512) = lv;                 // hl stride = 512 halves
  };

  auto tile = [&](int t, f16x8 (&bc)[4][2], f16x8 (&bn)[4][2], int rbuf) {
    __syncthreads();                 // A[rbuf] visible; prev-tile reads retired
    const bool more = (t + 1 < NT);
    f32x4 q0 = {}, q1 = {};
    if (more) {                      // x for tile t+1 (non-temporal stream)
      q0 = __builtin_nontemporal_load(xq);
      q1 = __builtin_nontemporal_load(xq + 1);
      xq += 16;                      // 64 floats
    }
#pragma unroll
    for (int s = 0; s < 4; ++s) {
      if (more) {                    // B for tile t+1, phase s (consumed next tile)
        const _Float16* bp = bb + (size_t)(4 * (t + 1) + s) * 8192;
        bn[s][0] = *(const f16x8*)bp;
        bn[s][1] = *(const f16x8*)(bp + 512);
      }
      const f16x8 a0h = *(const f16x8*)&a_st[rbuf][s][0][0][lane * 8];
      const f16x8 a0l = *(const f16x8*)&a_st[rbuf][s][0][1][lane * 8];
      const f16x8 a1h = *(const f16x8*)&a_st[rbuf][s][1][0][lane * 8];
      const f16x8 a1l = *(const f16x8*)&a_st[rbuf][s][1][1][lane * 8];
      accA[0] = __builtin_amdgcn_mfma_f32_32x32x16_f16(a0h, bc[s][0], accA[0], 0, 0, 0);
      accA[1] = __builtin_amdgcn_mfma_f32_32x32x16_f16(a1h, bc[s][0], accA[1], 0, 0, 0);
      accB[0] = __builtin_amdgcn_mfma_f32_32x32x16_f16(a0h, bc[s][1], accB[0], 0, 0, 0);
      accB[1] = __builtin_amdgcn_mfma_f32_32x32x16_f16(a1h, bc[s][1], accB[1], 0, 0, 0);
      accB[0] = __builtin_amdgcn_mfma_f32_32x32x16_f16(a0l, bc[s][0], accB[0], 0, 0, 0);
      accB[1] = __builtin_amdgcn_mfma_f32_32x32x16_f16(a1l, bc[s][0], accB[1], 0, 0, 0);
    }
    if (more) writeA(rbuf ^ 1, q0, q1);
  };

  // ---- prologue: A tile 0 staged into buf 0, B tile 0 into bE ----
  {
    const f32x4 q0 = __builtin_nontemporal_load(xq);
    const f32x4 q1 = __builtin_nontemporal_load(xq + 1);
    xq += 16;
    writeA(0, q0, q1);
#pragma unroll
    for (int s = 0; s < 4; ++s) {
      const _Float16* bp = bb + (size_t)s * 8192;
      bE[s][0] = *(const f16x8*)bp;
      bE[s][1] = *(const f16x8*)(bp + 512);
    }
  }

  // ---- main loop: 64 K-tiles, 1 barrier each, x2 unroll for static regs ----
#pragma unroll 1
  for (int tt = 0; tt < NT; tt += 2) {
    tile(tt, bE, bO, 0);
    tile(tt + 1, bO, bE, 1);
  }

  // ---- scores_for_choice into LDS ----
  // C layout (32x32 MFMA): col = lane&31, row = (r&3) + 8*(r>>2) + 4*(lane>>5)
  const int col = lane & 31;
  const int rbase = (lane >> 5) * 4;
  const int e = wave * 32 + col;
  const float be = sbias[e];
#pragma unroll
  for (int mt = 0; mt < 2; ++mt)
#pragma unroll
    for (int r = 0; r < 16; ++r) {
      const int row = (r & 3) + 8 * (r >> 2) + rbase;
      const float logit = accA[mt][r] + accB[mt][r] * LO_INV;
      const float s = 1.0f / (1.0f + expf(-logit));    // sigmoid
      val[mt * 32 + row][e] = s + be;                  // s_choice
    }
  __syncthreads();

  // ---- per-token grouped top-k (1 thread/token, lax.top_k semantics) ----
  if (tid < BM) {
    const int t = tid;
    float gs[NGROUP];
#pragma unroll
    for (int g = 0; g < NGROUP; ++g) {
      float m1 = -1e30f, m2 = -1e30f;
      for (int jj = 0; jj < GSIZE; ++jj) {
        const float v = val[t][g * GSIZE + jj];
        if (v > m1) { m2 = m1; m1 = v; }
        else if (v > m2) { m2 = v; }
      }
      gs[g] = m1 + m2;
    }
    unsigned selmask = 0;
#pragma unroll
    for (int r = 0; r < TOPK_GROUP; ++r) {
      float best = -1e30f; int bg = 0;
#pragma unroll
      for (int g = 0; g < NGROUP; ++g) {
        if (((selmask >> g) & 1u) == 0 && gs[g] > best) { best = gs[g]; bg = g; }
      }
      selmask |= 1u << bg;
    }
    unsigned long long picked[4] = {0ull, 0ull, 0ull, 0ull};
    int idx[TOPK];
    float wts[TOPK];
    float wsum = 0.f;
    for (int r = 0; r < TOPK; ++r) {
      float best = -1e30f; int be2 = 0; bool found = false;
      for (int ee = 0; ee < E; ++ee) {
        if ((picked[ee >> 6] >> (ee & 63)) & 1ull) continue;
        const float v = ((selmask >> (ee >> 5)) & 1u) ? val[t][ee] : 0.0f;
        if (!found || v > best) { best = v; be2 = ee; found = true; }
      }
      picked[be2 >> 6] |= 1ull << (be2 & 63);
      idx[r] = be2;
      const float s = val[t][be2] - sbias[be2];
      wts[r] = s;
      wsum += s;
    }
    const float inv = SCALE / (wsum + 1e-20f);
#pragma unroll
    for (int r = 0; r < TOPK; ++r) {
      out_idx[(t0 + t) * TOPK + r] = (float)idx[r];
      out_w[(t0 + t) * TOPK + r] = wts[r] * inv;
    }
  }
}

extern "C" void kernel_launch(void* const* d_in, const int* in_sizes, int n_in,
                              void* d_out, int out_size, void* d_ws, size_t ws_size,
                              hipStream_t stream) {
  const float* x = (const float*)d_in[0];     // (4,4096,4096) fp32
  const float* w = (const float*)d_in[1];     // (256,4096) fp32
  const float* bias = (const float*)d_in[2];  // (256,) fp32

  const int T = in_sizes[0] / H;              // 16384
  _Float16* wswz = (_Float16*)d_ws;           // 4 MB frag-linear hi/lo W
  float* out_idx = (float*)d_out;
  float* out_w = (float*)d_out + (size_t)T * TOPK;

  prep_w_kernel<<<dim3(NK16, E / 32), dim3(64), 0, stream>>>(w, wswz);
  moe_gate_kernel<<<dim3(T / BM), dim3(NTH), 0, stream>>>(x, wswz, bias, out_idx, out_w);
}